// Round 1
// baseline (554.101 us; speedup 1.0000x reference)
//
#include <hip/hip_runtime.h>
#include <math.h>

#define B 64
#define C 256
#define S 4096   // H*W = 64*64
#define S4 1024  // S/4 (float4 count per (b,c) plane)
#define NG 4     // channel groups for k1 partials
#define CPG 64   // channels per group (C/NG)

typedef float v4f __attribute__((ext_vector_type(4)));

// ---------------------------------------------------------------------------
// Kernel 1: partial channel reduce  tp[g,b,s] = sum_{c in group g} x[b,c,s]*w[c]
// grid = B * NG * 4 = 1024 blocks (4/CU, 16 waves/CU), 256 threads, float4/thread
// ---------------------------------------------------------------------------
__global__ __launch_bounds__(256) void k1_chanreduce(const float4* __restrict__ x4,
                                                     const float* __restrict__ cw,
                                                     float4* __restrict__ tp4) {
    __shared__ float wl[CPG];
    const int tid = threadIdx.x;
    const int bid = blockIdx.x;
    const int b = bid >> 4;
    const int cg = (bid >> 2) & (NG - 1);
    const int chunk = bid & 3;
    if (tid < CPG) wl[tid] = cw[cg * CPG + tid];
    __syncthreads();
    const int s4 = chunk * 256 + tid;
    const float4* xb = x4 + (size_t)b * C * S4 + (size_t)cg * CPG * S4 + s4;
    float4 acc = make_float4(0.f, 0.f, 0.f, 0.f);
#pragma unroll 8
    for (int c = 0; c < CPG; ++c) {
        float4 v = xb[(size_t)c * S4];
        float w = wl[c];
        acc.x += v.x * w; acc.y += v.y * w; acc.z += v.z * w; acc.w += v.w * w;
    }
    tp4[((size_t)cg * B + b) * S4 + s4] = acc;
}

// ---------------------------------------------------------------------------
// Kernel 2: fold NG partials + grouped 3x3x3 box-sum (zero pad, /27) + bias
//           + spatial softmax.  one block per batch, everything in LDS.
// ---------------------------------------------------------------------------
__global__ __launch_bounds__(256) void k2_pool_softmax(const float* __restrict__ tp,
                                                       const float* __restrict__ cb,
                                                       float* __restrict__ attn) {
    __shared__ float ts[S];    // depth-summed plane
    __shared__ float rs[S];    // + row (w) summed
    __shared__ float red[16];
    const int b = blockIdx.x;
    const int d = b & 7;       // depth index within group of 8
    const int tid = threadIdx.x;

    // fold channel-group partials + depth sum (b-1/b+1 stay in group iff d>0/d<7)
    for (int k = 0; k < 16; ++k) {
        int s = k * 256 + tid;
        float v = 0.f;
#pragma unroll
        for (int g = 0; g < NG; ++g) {
            const float* t0 = tp + ((size_t)g * B + b) * S + s;
            float u = t0[0];
            if (d > 0) u += t0[-S];
            if (d < 7) u += t0[S];
            v += u;
        }
        ts[s] = v;
    }
    __syncthreads();
    // w-direction sum (zero at borders)
    for (int k = 0; k < 16; ++k) {
        int s = k * 256 + tid;
        int w = s & 63;
        float v = ts[s];
        if (w > 0)  v += ts[s - 1];
        if (w < 63) v += ts[s + 1];
        rs[s] = v;
    }
    __syncthreads();
    // h-direction sum, /27, +bias -> logits (registers)
    const float bias = cb[0];
    float l[16];
    float m = -INFINITY;
    for (int k = 0; k < 16; ++k) {
        int s = k * 256 + tid;
        float v = rs[s];
        if (s >= 64)     v += rs[s - 64];
        if (s < S - 64)  v += rs[s + 64];
        l[k] = v * (1.0f / 27.0f) + bias;
        m = fmaxf(m, l[k]);
    }
    // block max
    for (int o = 32; o > 0; o >>= 1) m = fmaxf(m, __shfl_xor(m, o));
    const int wave = tid >> 6;
    if ((tid & 63) == 0) red[wave] = m;
    __syncthreads();
    if (tid == 0) {
        float mm = red[0];
        for (int i = 1; i < 4; ++i) mm = fmaxf(mm, red[i]);
        red[8] = mm;
    }
    __syncthreads();
    m = red[8];
    // exp + block sum
    float sum = 0.f;
    for (int k = 0; k < 16; ++k) { l[k] = expf(l[k] - m); sum += l[k]; }
    for (int o = 32; o > 0; o >>= 1) sum += __shfl_xor(sum, o);
    if ((tid & 63) == 0) red[wave] = sum;
    __syncthreads();
    if (tid == 0) {
        float ss = red[0] + red[1] + red[2] + red[3];
        red[9] = 1.0f / ss;
    }
    __syncthreads();
    const float inv = red[9];
    float* ab = attn + (size_t)b * S;
    for (int k = 0; k < 16; ++k) {
        int s = k * 256 + tid;
        ab[s] = l[k] * inv;
    }
}

// ---------------------------------------------------------------------------
// Kernel 3: y[b,c] = sum_s x[b,c,s] * attn[b,s]
// grid = 4096 blocks (b * 64 channel-groups of 4), 256 threads = 4 waves,
// one wave per channel; attn read direct from global (L2-resident, 1 MiB),
// no LDS, no barrier -> 32 waves/CU residency
// ---------------------------------------------------------------------------
__global__ __launch_bounds__(256) void k3_weighted_pool(const float4* __restrict__ x4,
                                                        const float4* __restrict__ attn4,
                                                        float* __restrict__ y) {
    const int tid = threadIdx.x;
    const int b = blockIdx.x >> 6;
    const int cg = blockIdx.x & 63;
    const int c = cg * 4 + (tid >> 6);
    const int lane = tid & 63;
    const float4* xb = x4 + ((size_t)(b * C + c)) * S4;
    const float4* ab = attn4 + (size_t)b * S4;
    float acc = 0.f;
#pragma unroll 4
    for (int it = 0; it < 16; ++it) {
        int s4 = it * 64 + lane;
        float4 xv = xb[s4];
        float4 av = ab[s4];
        acc += xv.x * av.x + xv.y * av.y + xv.z * av.z + xv.w * av.w;
    }
#pragma unroll
    for (int o = 32; o > 0; o >>= 1) acc += __shfl_xor(acc, o);
    if (lane == 0) y[b * C + c] = acc;
}

// ---------------------------------------------------------------------------
// Kernel 4: SE MLP  hid = relu(y @ fc1^T), gate = sigmoid(hid @ fc2^T)
// one block per batch (64 blocks, 256 threads)
// ---------------------------------------------------------------------------
__global__ __launch_bounds__(256) void k4_mlp(const float* __restrict__ y,
                                              const float* __restrict__ fc1,
                                              const float* __restrict__ fc2,
                                              float* __restrict__ gate) {
    __shared__ float yl[C];
    __shared__ float ph[16][17];   // +1 pad
    __shared__ float hid[16];
    const int b = blockIdx.x;
    const int tid = threadIdx.x;
    yl[tid] = y[(size_t)b * C + tid];
    __syncthreads();
    const int j = tid >> 4, part = tid & 15;
    float p = 0.f;
#pragma unroll
    for (int k = 0; k < 16; ++k) {
        int cc = part + k * 16;
        p += yl[cc] * fc1[j * C + cc];
    }
    ph[j][part] = p;
    __syncthreads();
    if (tid < 16) {
        float s = 0.f;
#pragma unroll
        for (int k = 0; k < 16; ++k) s += ph[tid][k];
        hid[tid] = fmaxf(s, 0.f);
    }
    __syncthreads();
    float g = 0.f;
#pragma unroll
    for (int jj = 0; jj < 16; ++jj) g += hid[jj] * fc2[tid * 16 + jj];
    gate[(size_t)b * C + tid] = 1.0f / (1.0f + expf(-g));
}

// ---------------------------------------------------------------------------
// Kernel 5: out = x * gate[b,c]  — pure stream, nontemporal ld/st, unrolled
// grid = 4096 blocks x 256 threads x 16 iters = 16,777,216 float4 = B*C*S4
// ---------------------------------------------------------------------------
__global__ __launch_bounds__(256) void k5_scale(const v4f* __restrict__ x4,
                                               const float* __restrict__ gate,
                                               v4f* __restrict__ out4) {
    size_t i = (size_t)blockIdx.x * 256 + threadIdx.x;
    const size_t stride = (size_t)4096 * 256;   // 1,048,576 float4
#pragma unroll 4
    for (int it = 0; it < 16; ++it, i += stride) {
        float g = gate[(int)(i >> 10)];         // 1024 float4 per (b,c) plane
        v4f v = __builtin_nontemporal_load(&x4[i]);
        v *= g;
        __builtin_nontemporal_store(v, &out4[i]);
    }
}

extern "C" void kernel_launch(void* const* d_in, const int* in_sizes, int n_in,
                              void* d_out, int out_size, void* d_ws, size_t ws_size,
                              hipStream_t stream) {
    const float* x   = (const float*)d_in[0];
    const float* cw  = (const float*)d_in[1];
    const float* cb  = (const float*)d_in[2];
    const float* fc1 = (const float*)d_in[3];
    const float* fc2 = (const float*)d_in[4];
    float* out = (float*)d_out;

    // workspace (fp32): tp[NG*64*4096] | attn[64*4096] | y[64*256] | gate[64*256]
    float* tp   = (float*)d_ws;
    float* attn = tp + (size_t)NG * B * S;
    float* y    = attn + (size_t)B * S;
    float* gate = y + (size_t)B * C;

    k1_chanreduce<<<B * NG * 4, 256, 0, stream>>>((const float4*)x, cw, (float4*)tp);
    k2_pool_softmax<<<B, 256, 0, stream>>>(tp, cb, attn);
    k3_weighted_pool<<<B * 64, 256, 0, stream>>>((const float4*)x, (const float4*)attn, y);
    k4_mlp<<<B, 256, 0, stream>>>(y, fc1, fc2, gate);
    k5_scale<<<4096, 256, 0, stream>>>((const v4f*)x, gate, (v4f*)out);
}

// Round 2
// 533.806 us; speedup vs baseline: 1.0380x; 1.0380x over previous
//
#include <hip/hip_runtime.h>
#include <math.h>

#define B 64
#define C 256
#define S 4096   // H*W = 64*64
#define S4 1024  // S/4 (float4 count per (b,c) plane)

typedef float v4f __attribute__((ext_vector_type(4)));

// ---------------------------------------------------------------------------
// Kernel 1: channel reduce  t[b,s] = sum_c x[b,c,s] * conv_w[c]
// grid = B*16 = 1024 blocks (4/CU), 256 threads.
// Block covers 64 float4 positions; 4 waves each sum 64 channels, LDS-reduce.
// ---------------------------------------------------------------------------
__global__ __launch_bounds__(256) void k1_chanreduce(const float4* __restrict__ x4,
                                                     const float* __restrict__ cw,
                                                     float4* __restrict__ t4) {
    __shared__ float4 sh[256];
    const int tid = threadIdx.x;
    const int b = blockIdx.x >> 4;
    const int chunk = blockIdx.x & 15;
    const int cg = tid >> 6;          // wave id = channel group
    const int s4i = tid & 63;
    const int s4 = chunk * 64 + s4i;
    const float4* xb = x4 + (size_t)b * C * S4 + (size_t)cg * 64 * S4 + s4;
    float4 acc = make_float4(0.f, 0.f, 0.f, 0.f);
#pragma unroll 8
    for (int k = 0; k < 64; ++k) {
        float4 v = xb[(size_t)k * S4];
        float w = cw[cg * 64 + k];    // wave-uniform -> scalar load
        acc.x += v.x * w; acc.y += v.y * w; acc.z += v.z * w; acc.w += v.w * w;
    }
    sh[tid] = acc;
    __syncthreads();
    if (cg == 0) {
        float4 a = sh[s4i], b2 = sh[64 + s4i], c2 = sh[128 + s4i], d2 = sh[192 + s4i];
        float4 r;
        r.x = a.x + b2.x + c2.x + d2.x;
        r.y = a.y + b2.y + c2.y + d2.y;
        r.z = a.z + b2.z + c2.z + d2.z;
        r.w = a.w + b2.w + c2.w + d2.w;
        t4[(size_t)b * S4 + s4] = r;
    }
}

// ---------------------------------------------------------------------------
// Kernel 2: grouped 3x3x3 box-sum (zero pad, /27) + bias + spatial softmax
// one block per batch (64 blocks, 256 threads), everything in LDS
// ---------------------------------------------------------------------------
__global__ __launch_bounds__(256) void k2_pool_softmax(const float* __restrict__ t,
                                                       const float* __restrict__ cb,
                                                       float* __restrict__ attn) {
    __shared__ float ts[S];    // depth-summed plane
    __shared__ float rs[S];    // + row (w) summed
    __shared__ float red[16];
    const int b = blockIdx.x;
    const int d = b & 7;       // depth index within group of 8
    const int tid = threadIdx.x;
    const float* t0 = t + (size_t)b * S;

    // depth sum: neighbors b-1 / b+1 stay inside the group iff d>0 / d<7
    for (int k = 0; k < 16; ++k) {
        int s = k * 256 + tid;
        float v = t0[s];
        if (d > 0) v += t0[s - S];
        if (d < 7) v += t0[s + S];
        ts[s] = v;
    }
    __syncthreads();
    // w-direction sum (zero at borders)
    for (int k = 0; k < 16; ++k) {
        int s = k * 256 + tid;
        int w = s & 63;
        float v = ts[s];
        if (w > 0)  v += ts[s - 1];
        if (w < 63) v += ts[s + 1];
        rs[s] = v;
    }
    __syncthreads();
    // h-direction sum, /27, +bias -> logits (registers)
    const float bias = cb[0];
    float l[16];
    float m = -INFINITY;
    for (int k = 0; k < 16; ++k) {
        int s = k * 256 + tid;
        float v = rs[s];
        if (s >= 64)     v += rs[s - 64];
        if (s < S - 64)  v += rs[s + 64];
        l[k] = v * (1.0f / 27.0f) + bias;
        m = fmaxf(m, l[k]);
    }
    // block max
    for (int o = 32; o > 0; o >>= 1) m = fmaxf(m, __shfl_xor(m, o));
    const int wave = tid >> 6;
    if ((tid & 63) == 0) red[wave] = m;
    __syncthreads();
    if (tid == 0) {
        float mm = red[0];
        for (int i = 1; i < 4; ++i) mm = fmaxf(mm, red[i]);
        red[8] = mm;
    }
    __syncthreads();
    m = red[8];
    // exp + block sum
    float sum = 0.f;
    for (int k = 0; k < 16; ++k) { l[k] = expf(l[k] - m); sum += l[k]; }
    for (int o = 32; o > 0; o >>= 1) sum += __shfl_xor(sum, o);
    if ((tid & 63) == 0) red[wave] = sum;
    __syncthreads();
    if (tid == 0) {
        float ss = red[0] + red[1] + red[2] + red[3];
        red[9] = 1.0f / ss;
    }
    __syncthreads();
    const float inv = red[9];
    float* ab = attn + (size_t)b * S;
    for (int k = 0; k < 16; ++k) {
        int s = k * 256 + tid;
        ab[s] = l[k] * inv;
    }
}

// ---------------------------------------------------------------------------
// Kernel 3: y[b,c] = sum_s x[b,c,s] * attn[b,s]
// grid = 4096 blocks, 4 waves/block, one channel per wave, attn from L2.
// Batch order REVERSED: k1 finished with the tail of x (high b) L3-resident,
// so start there; we end at b=0, leaving low-b x in L3 for k5 (ascending).
// ---------------------------------------------------------------------------
__global__ __launch_bounds__(256) void k3_weighted_pool(const float4* __restrict__ x4,
                                                        const float4* __restrict__ attn4,
                                                        float* __restrict__ y) {
    const int tid = threadIdx.x;
    const int b = (B - 1) - (blockIdx.x >> 6);   // reversed
    const int cg = blockIdx.x & 63;
    const int c = cg * 4 + (tid >> 6);
    const int lane = tid & 63;
    const float4* xb = x4 + ((size_t)(b * C + c)) * S4;
    const float4* ab = attn4 + (size_t)b * S4;
    float acc = 0.f;
#pragma unroll 4
    for (int it = 0; it < 16; ++it) {
        int s4 = it * 64 + lane;
        float4 xv = xb[s4];
        float4 av = ab[s4];
        acc += xv.x * av.x + xv.y * av.y + xv.z * av.z + xv.w * av.w;
    }
#pragma unroll
    for (int o = 32; o > 0; o >>= 1) acc += __shfl_xor(acc, o);
    if (lane == 0) y[b * C + c] = acc;
}

// ---------------------------------------------------------------------------
// Kernel 5 (fused MLP + scale): each block (b, chunk) redundantly computes
// gate[b,:] from y (8K MACs, ~1 us) then streams its 1/16 of the plane set.
// grid = B*16 = 1024 blocks, 256 threads; 1 KB contiguous per wave-load.
// ---------------------------------------------------------------------------
__global__ __launch_bounds__(256) void k5_mlp_scale(const v4f* __restrict__ x4,
                                                    const float* __restrict__ y,
                                                    const float* __restrict__ fc1,
                                                    const float* __restrict__ fc2,
                                                    v4f* __restrict__ out4) {
    __shared__ float yl[C];
    __shared__ float ph[16][17];
    __shared__ float hid[16];
    __shared__ float gl[C];
    const int tid = threadIdx.x;
    const int b = blockIdx.x >> 4;
    const int chunk = blockIdx.x & 15;

    yl[tid] = y[(size_t)b * C + tid];
    __syncthreads();
    // hid = relu(y @ fc1^T): 16 outputs, 16-way partial each
    {
        const int j = tid >> 4, part = tid & 15;
        float p = 0.f;
#pragma unroll
        for (int k = 0; k < 16; ++k) {
            int cc = part + k * 16;
            p += yl[cc] * fc1[j * C + cc];
        }
        ph[j][part] = p;
    }
    __syncthreads();
    if (tid < 16) {
        float s = 0.f;
#pragma unroll
        for (int k = 0; k < 16; ++k) s += ph[tid][k];
        hid[tid] = fmaxf(s, 0.f);
    }
    __syncthreads();
    {
        float g = 0.f;
#pragma unroll
        for (int jj = 0; jj < 16; ++jj) g += hid[jj] * fc2[tid * 16 + jj];
        gl[tid] = 1.0f / (1.0f + expf(-g));
    }
    __syncthreads();

    // stream: this block covers s4 in [chunk*64, chunk*64+64) for all 256 ch
    const int s4i = tid & 63;
    const int cw_ = tid >> 6;
    const size_t base = (size_t)b * C * S4 + (size_t)chunk * 64 + s4i;
#pragma unroll 4
    for (int it = 0; it < 64; ++it) {
        int ch = it * 4 + cw_;                    // wave-uniform
        float g = gl[ch];
        size_t idx = base + (size_t)ch * S4;
        v4f v = __builtin_nontemporal_load(&x4[idx]);
        v *= g;
        __builtin_nontemporal_store(v, &out4[idx]);
    }
}

extern "C" void kernel_launch(void* const* d_in, const int* in_sizes, int n_in,
                              void* d_out, int out_size, void* d_ws, size_t ws_size,
                              hipStream_t stream) {
    const float* x   = (const float*)d_in[0];
    const float* cw  = (const float*)d_in[1];
    const float* cb  = (const float*)d_in[2];
    const float* fc1 = (const float*)d_in[3];
    const float* fc2 = (const float*)d_in[4];
    float* out = (float*)d_out;

    // workspace (fp32): t[64*4096] | attn[64*4096] | y[64*256]
    float* t    = (float*)d_ws;
    float* attn = t + (size_t)B * S;
    float* y    = attn + (size_t)B * S;

    k1_chanreduce<<<B * 16, 256, 0, stream>>>((const float4*)x, cw, (float4*)t);
    k2_pool_softmax<<<B, 256, 0, stream>>>(t, cb, attn);
    k3_weighted_pool<<<B * 64, 256, 0, stream>>>((const float4*)x, (const float4*)attn, y);
    k5_mlp_scale<<<B * 16, 256, 0, stream>>>((const v4f*)x, y, fc1, fc2, (v4f*)out);
}